// Round 6
// baseline (731.536 us; speedup 1.0000x reference)
//
#include <hip/hip_runtime.h>
#include <hip/hip_bf16.h>
#include <math.h>

#define N_Q 2048
#define K_E 32
#define D_F 128
#define H_N 8
#define DH_N 16
#define EPS_F 1e-5f
#define NEGMAX -3.4028235e38f
#define EPB 8      // edges per edge-block

// R17: revert stage-A to VALU (R15/R16 MFMA layout debugging abandoned after
// two structural fails; probe experiment proved the HW layout deviates from
// the documented model in a way probes can't fully recover). New lever:
// one-time k_packw repacks ALL weights into per-thread access order:
//  - WdtpT[col][k]   : stage-A column-major -> float4 loads (128->32 /thread)
//  - WqP/WkP/WoP     : [out][in][2] float2 rows (256->128 loads /thread)
//  - wqk2/wval2      : (s,v) float2          (2 loads -> 1 /iter)
//  - wagv4           : (s0,s1,s2,v) float4   (4 loads -> 1 /iter)
// Arithmetic bit-identical to R14/R3 (same values, same order).

// ---------------------------------------------------------------------------
// k_packw: one-time weight repack into workspace (280576 floats ~ 1.1 MB).
// Segments (float offsets): WdtpT 0, WqP 65536, WkP 131072, WoP 196608,
// wqk2 262144, wagv4 263168, wval2 279552.
// ---------------------------------------------------------------------------
__global__ __launch_bounds__(256) void k_packw(
    const float* __restrict__ Wdtp,
    const float* __restrict__ Wq_s, const float* __restrict__ Wq_v,
    const float* __restrict__ Wk_s, const float* __restrict__ Wk_v,
    const float* __restrict__ Wo_s, const float* __restrict__ Wo_v,
    const float* __restrict__ Wqk_s, const float* __restrict__ Wqk_v,
    const float* __restrict__ Wagv_s, const float* __restrict__ Wagv_v,
    const float* __restrict__ Wval_s, const float* __restrict__ Wval_v,
    float* __restrict__ wpk)
{
    const int idx = blockIdx.x*256 + threadIdx.x;
    if (idx < 65536) {
        // WdtpT[t*128 + i] = Wdtp[i*512 + t]
        int i = idx & 127, t = idx >> 7;
        wpk[idx] = Wdtp[(size_t)i*512 + t];
    } else if (idx < 131072) {
        int x = idx - 65536; int p = x >> 1, comp = x & 1;
        int t = p >> 7, i = p & 127;
        wpk[idx] = comp ? Wq_v[i*128 + t] : Wq_s[i*128 + t];
    } else if (idx < 196608) {
        int x = idx - 131072; int p = x >> 1, comp = x & 1;
        int t = p >> 7, i = p & 127;
        wpk[idx] = comp ? Wk_v[i*128 + t] : Wk_s[i*128 + t];
    } else if (idx < 262144) {
        int x = idx - 196608; int p = x >> 1, comp = x & 1;
        int t = p >> 7, i = p & 127;
        wpk[idx] = comp ? Wo_v[i*128 + t] : Wo_s[i*128 + t];
    } else if (idx < 263168) {
        int x = idx - 262144; int p = x >> 1, comp = x & 1;   // p = i*16+o
        wpk[idx] = comp ? Wqk_v[p] : Wqk_s[p];
    } else if (idx < 279552) {
        int x = idx - 263168; int e = x >> 2, comp = x & 3;   // e = (h*32+i)*16+o
        int row = e >> 4, o = e & 15;
        wpk[idx] = (comp < 3) ? Wagv_s[row*48 + comp*16 + o] : Wagv_v[row*16 + o];
    } else if (idx < 280576) {
        int x = idx - 279552; int p = x >> 1, comp = x & 1;
        wpk[idx] = comp ? Wval_v[p] : Wval_s[p];
    }
}

// ---------------------------------------------------------------------------
// Kernel A+B: query LN+Wq (blocks [0,N)) / key Wk (blocks [N,2N)).
// Outputs packed float4: .xyz = vector part, .w = scalar part.
// ---------------------------------------------------------------------------
__global__ __launch_bounds__(128) void k_qk(
    const float* __restrict__ qs_in, const float* __restrict__ qv_in,
    const float* __restrict__ ks_in, const float* __restrict__ kv_in,
    const float* __restrict__ WqP, const float* __restrict__ bq,
    const float* __restrict__ WkP, const float* __restrict__ bk,
    const float* __restrict__ ln_gs, const float* __restrict__ ln_bs, const float* __restrict__ ln_gv,
    float4* __restrict__ q4, float4* __restrict__ k4,
    float* __restrict__ skip_s, float* __restrict__ skip_v)
{
    const int t = threadIdx.x;
    __shared__ __align__(16) float raw[D_F*3];
    __shared__ float4 sv[D_F];
    __shared__ float red[6];
    if (blockIdx.x < N_Q) {
        const int n = blockIdx.x;
        float sval = qs_in[n*D_F + t];
        float ssqp = 0.f;
        if (t < 96) {
            float4 rv = ((const float4*)(qv_in + (size_t)n*D_F*3))[t];
            ((float4*)raw)[t] = rv;
            ssqp = rv.x*rv.x + rv.y*rv.y + rv.z*rv.z + rv.w*rv.w;
        }
        float r0 = sval, r1 = sval*sval, r2 = ssqp;
        #pragma unroll
        for (int m = 1; m < 64; m <<= 1) {
            r0 += __shfl_xor(r0, m);
            r1 += __shfl_xor(r1, m);
            r2 += __shfl_xor(r2, m);
        }
        if ((t & 63) == 0) { int w = t >> 6; red[w*3+0]=r0; red[w*3+1]=r1; red[w*3+2]=r2; }
        __syncthreads();
        float tS = red[0]+red[3], tS2 = red[1]+red[4], tQ = red[2]+red[5];
        float mu = tS * (1.f/D_F);
        float var = fmaxf(tS2*(1.f/D_F) - mu*mu, 0.f);
        float rstd = rsqrtf(var + EPS_F);
        float rrms = rsqrtf(tQ*(1.f/D_F) + EPS_F);
        float a = (sval - mu)*rstd*ln_gs[t] + ln_bs[t];
        skip_s[n*D_F + t] = a;
        float gv = ln_gv[t];
        float b0 = raw[t*3+0]*rrms*gv;
        float b1 = raw[t*3+1]*rrms*gv;
        float b2 = raw[t*3+2]*rrms*gv;
        skip_v[(n*D_F + t)*3 + 0] = b0;
        skip_v[(n*D_F + t)*3 + 1] = b1;
        skip_v[(n*D_F + t)*3 + 2] = b2;
        sv[t] = make_float4(b0, b1, b2, a);
        __syncthreads();
        const float2* wp = ((const float2*)WqP) + (size_t)t*128;
        float acc = bq[t], a0 = 0.f, a1 = 0.f, a2 = 0.f;
        #pragma unroll 4
        for (int i = 0; i < D_F; ++i) {
            float4 p = sv[i];
            float2 w = wp[i];
            acc += p.w*w.x; a0 += p.x*w.y; a1 += p.y*w.y; a2 += p.z*w.y;
        }
        q4[n*D_F + t] = make_float4(a0, a1, a2, acc);
    } else {
        const int n = blockIdx.x - N_Q;
        float sval = ks_in[n*D_F + t];
        if (t < 96) ((float4*)raw)[t] = ((const float4*)(kv_in + (size_t)n*D_F*3))[t];
        __syncthreads();
        sv[t] = make_float4(raw[t*3+0], raw[t*3+1], raw[t*3+2], sval);
        __syncthreads();
        const float2* wp = ((const float2*)WkP) + (size_t)t*128;
        float acc = bk[t], a0 = 0.f, a1 = 0.f, a2 = 0.f;
        #pragma unroll 4
        for (int i = 0; i < D_F; ++i) {
            float4 p = sv[i];
            float2 w = wp[i];
            acc += p.w*w.x; a0 += p.x*w.y; a1 += p.y*w.y; a2 += p.z*w.y;
        }
        k4[n*D_F + t] = make_float4(a0, a1, a2, acc);
    }
}

// ---------------------------------------------------------------------------
// k_edge_flash: R14 pipeline (8 edges/block, 2 per thread) + flash partial
// reduction tail, all weight streams packed.
// ---------------------------------------------------------------------------
__global__ __launch_bounds__(512, 6) void k_edge_flash(
    const float4* __restrict__ q4, const float4* __restrict__ k4,
    const float* __restrict__ eis, const float* __restrict__ eiv,
    const float* __restrict__ eemb,
    const int* __restrict__ mask, const int* __restrict__ knn,
    const float* __restrict__ wqk2, const float* __restrict__ bqk,
    const float* __restrict__ WdtpT, const float* __restrict__ bdtp,
    const float* __restrict__ wagv4, const float* __restrict__ bagv,
    const float* __restrict__ Wattn, const float* __restrict__ lna_g, const float* __restrict__ lna_b,
    const float* __restrict__ wval2, const float* __restrict__ bval,
    float4* __restrict__ pbuf, float* __restrict__ mbuf, float* __restrict__ attn_raw)
{
    const int t = threadIdx.x;
    const int e0 = blockIdx.x * EPB;
    const int n  = e0 >> 5;
    const int k0 = e0 & 31;
    const int g  = k0 >> 3;            // group index within n
    const int s = t >> 7, c = t & 127, h = (t >> 4) & 7, o = t & 15;
    const int rot2 = h * 2;

    __shared__ float4 ch[EPB*256];     // 32 KB (stage-A ee aliased here)
    __shared__ float4 w4[EPB*128];     // 16 KB; reused as partial-combine stage
    __shared__ float  afeat[EPB*8*17]; // 4.25 KB: 16 feats + logit col 16
    __shared__ float  mred[16];        // Mg[8], deng[8]

    // stage A: ee load (transposed, aliased into ch) + w GEMM, float4 weights
    {
        float* ee = (float*)ch;        // [128][8] floats = 4 KB
        { int idx = t;       int m = idx & 7, i = idx >> 3; ee[i*EPB+m] = eemb[(size_t)(e0+m)*D_F + i]; }
        { int idx = t + 512; int m = idx & 7, i = idx >> 3; ee[i*EPB+m] = eemb[(size_t)(e0+m)*D_F + i]; }
        __syncthreads();
        float acc[EPB];
        float b = bdtp[t];
        #pragma unroll
        for (int m = 0; m < EPB; ++m) acc[m] = b;
        const float4* wcol = (const float4*)(WdtpT + (size_t)t*128);
        #pragma unroll 2
        for (int i4 = 0; i4 < 32; ++i4) {
            float4 wv4 = wcol[i4];
            const float* eb = ee + i4*32;
            #pragma unroll
            for (int m = 0; m < EPB; ++m) acc[m] += eb[m]      * wv4.x;
            #pragma unroll
            for (int m = 0; m < EPB; ++m) acc[m] += eb[8 + m]  * wv4.y;
            #pragma unroll
            for (int m = 0; m < EPB; ++m) acc[m] += eb[16 + m] * wv4.z;
            #pragma unroll
            for (int m = 0; m < EPB; ++m) acc[m] += eb[24 + m] * wv4.w;
        }
        __syncthreads();               // all ee reads done -> ch reusable
        float* w4f = (float*)w4;
        const int chn = t & 127, sel = t >> 7;
        #pragma unroll
        for (int m = 0; m < EPB; ++m)
            w4f[(m*128 + chn)*4 + sel] = acc[m];
    }

    const int mA = s, mB = s + 4;
    const int eA = e0 + mA, eB = e0 + mB;

    const float esA = eis[eA], esB = eis[eB];
    const float evAx = eiv[eA*3+0], evAy = eiv[eA*3+1], evAz = eiv[eA*3+2];
    const float evBx = eiv[eB*3+0], evBy = eiv[eB*3+1], evBz = eiv[eB*3+2];

    // B1: dtp1 straight from global
    {
        float4 q  = q4[(size_t)n*D_F + c];
        float4 kA = k4[(size_t)knn[eA]*D_F + c];
        float4 kB = k4[(size_t)knn[eB]*D_F + c];
        const int hp = c >> 5, jc = c & 31;
        const int pos0 = hp*32 + ((jc + 2*hp) & 31);
        const int pos1 = (hp+4)*32 + ((jc + 2*(hp+4)) & 31);
        ch[mA*256 + pos0] = make_float4(q.w*kA.x, q.w*kA.y, q.w*kA.z, q.w*kA.w);
        ch[mA*256 + pos1] = make_float4(kA.w*q.x, kA.w*q.y, kA.w*q.z,
                                        q.x*kA.x + q.y*kA.y + q.z*kA.z);
        ch[mB*256 + pos0] = make_float4(q.w*kB.x, q.w*kB.y, q.w*kB.z, q.w*kB.w);
        ch[mB*256 + pos1] = make_float4(kB.w*q.x, kB.w*q.y, kB.w*q.z,
                                        q.x*kB.x + q.y*kB.y + q.z*kB.z);
    }
    __syncthreads();

    const int chA = mA*256 + h*32, chB = mB*256 + h*32;

    // B2: Wqk — packed float2 weights
    float pAs, pA0, pA1, pA2, pBs, pB0, pB1, pB2;
    {
        const float2* wqk = (const float2*)wqk2;
        const float bqk_r = bqk[o];
        pAs = bqk_r; pA0 = 0.f; pA1 = 0.f; pA2 = 0.f;
        pBs = bqk_r; pB0 = 0.f; pB1 = 0.f; pB2 = 0.f;
        #pragma unroll 4
        for (int i = 0; i < 32; ++i) {
            int ph = (i + rot2) & 31;
            float4 cA = ch[chA + ph];
            float4 cB = ch[chB + ph];
            float2 w = wqk[i*16 + o];
            pAs += cA.w*w.x; pA0 += cA.x*w.y; pA1 += cA.y*w.y; pA2 += cA.z*w.y;
            pBs += cB.w*w.x; pB0 += cB.x*w.y; pB1 += cB.y*w.y; pB2 += cB.z*w.y;
        }
    }
    __syncthreads();

    const int posA = h*32 + ((o + rot2) & 31);
    const int posB = h*32 + ((o + 16 + rot2) & 31);

    // B3: dtp2 (weighted)
    {
        float4 wA = w4[mA*128 + c];
        float4 wB = w4[mB*128 + c];
        ch[mA*256 + posA] = make_float4(pAs*evAx*wA.z, pAs*evAy*wA.z, pAs*evAz*wA.z, pAs*esA*wA.x);
        float dA = pA0*evAx + pA1*evAy + pA2*evAz;
        ch[mA*256 + posB] = make_float4(esA*pA0*wA.w, esA*pA1*wA.w, esA*pA2*wA.w, dA*wA.y);
        ch[mB*256 + posA] = make_float4(pBs*evBx*wB.z, pBs*evBy*wB.z, pBs*evBz*wB.z, pBs*esB*wB.x);
        float dB = pB0*evBx + pB1*evBy + pB2*evBz;
        ch[mB*256 + posB] = make_float4(esB*pB0*wB.w, esB*pB1*wB.w, esB*pB2*wB.w, dB*wB.y);
    }
    __syncthreads();

    // B4: Wagv — packed float4 weights (one load per iteration)
    float gtA, vlA, vA0, vA1, vA2, gtB, vlB, vB0, vB1, vB2;
    {
        const float4* wag = (const float4*)wagv4;
        const float bag0 = bagv[h*48 + o];
        const float bag1 = bagv[h*48 + 16 + o];
        const float bag2 = bagv[h*48 + 32 + o];
        float atA = bag0, atB = bag0;
        gtA = bag1; vlA = bag2; vA0 = 0.f; vA1 = 0.f; vA2 = 0.f;
        gtB = bag1; vlB = bag2; vB0 = 0.f; vB1 = 0.f; vB2 = 0.f;
        #pragma unroll 4
        for (int i = 0; i < 32; ++i) {
            int ph = (i + rot2) & 31;
            float4 cA = ch[chA + ph];
            float4 cB = ch[chB + ph];
            float4 wg = wag[(h*32+i)*16 + o];
            atA += cA.w*wg.x; gtA += cA.w*wg.y; vlA += cA.w*wg.z;
            vA0 += cA.x*wg.w; vA1 += cA.y*wg.w; vA2 += cA.z*wg.w;
            atB += cB.w*wg.x; gtB += cB.w*wg.y; vlB += cB.w*wg.z;
            vB0 += cB.x*wg.w; vB1 += cB.y*wg.w; vB2 += cB.z*wg.w;
        }
        afeat[(mA*8 + h)*17 + o] = atA;
        afeat[(mB*8 + h)*17 + o] = atB;
    }
    __syncthreads();

    // B5: logits (wave 0: 8 edges x 8 heads) + group max/den via shuffles
    if (t < EPB*H_N) {
        int m2 = t >> 3, h2 = t & 7;
        const float* afr = &afeat[(m2*8 + h2)*17];
        float mu = 0.f;
        #pragma unroll 4
        for (int d2 = 0; d2 < DH_N; ++d2) mu += afr[d2];
        mu *= (1.f/DH_N);
        float var = 0.f;
        #pragma unroll 4
        for (int d2 = 0; d2 < DH_N; ++d2) { float dd = afr[d2]-mu; var += dd*dd; }
        var *= (1.f/DH_N);
        float rstd = rsqrtf(var + EPS_F);
        float logit = 0.f;
        #pragma unroll 4
        for (int d2 = 0; d2 < DH_N; ++d2) {
            float xn = (afr[d2]-mu)*rstd*lna_g[d2] + lna_b[d2];
            logit += xn*Wattn[d2];
        }
        if (mask[e0 + m2] == 0) logit = NEGMAX;
        attn_raw[h2*(N_Q*K_E) + n*K_E + (k0 + m2)] = logit;
        afeat[(m2*8 + h2)*17 + 16] = logit;
        float mx = logit;
        mx = fmaxf(mx, __shfl_xor(mx, 8));
        mx = fmaxf(mx, __shfl_xor(mx, 16));
        mx = fmaxf(mx, __shfl_xor(mx, 32));
        float ex = expf(logit - mx);
        ex += __shfl_xor(ex, 8);
        ex += __shfl_xor(ex, 16);
        ex += __shfl_xor(ex, 32);
        if (m2 == 0) { mred[h2] = mx; mred[8 + h2] = ex; }
    }
    // gating (register-only, all threads)
    float sactA = vlA / (1.f + expf(-vlA));
    float gA = 1.f / (1.f + expf(-gtA));
    float qA0 = vA0*gA, qA1 = vA1*gA, qA2 = vA2*gA;
    float sactB = vlB / (1.f + expf(-vlB));
    float gB = 1.f / (1.f + expf(-gtB));
    float qB0 = vB0*gB, qB1 = vB1*gB, qB2 = vB2*gB;

    // B6: dtp3
    {
        ch[mA*256 + posA] = make_float4(sactA*evAx, sactA*evAy, sactA*evAz, sactA*esA);
        float dA = qA0*evAx + qA1*evAy + qA2*evAz;
        ch[mA*256 + posB] = make_float4(esA*qA0, esA*qA1, esA*qA2, dA);
        ch[mB*256 + posA] = make_float4(sactB*evBx, sactB*evBy, sactB*evBz, sactB*esB);
        float dB = qB0*evBx + qB1*evBy + qB2*evBz;
        ch[mB*256 + posB] = make_float4(esB*qB0, esB*qB1, esB*qB2, dB);
    }
    __syncthreads();

    // B7: Wval -> registers, weight by exp(logit - Mg), stage partial in w4
    {
        const float2* wvl = (const float2*)wval2;
        const float bval_r = bval[o];
        float vsA = bval_r, uA0 = 0.f, uA1 = 0.f, uA2 = 0.f;
        float vsB = bval_r, uB0 = 0.f, uB1 = 0.f, uB2 = 0.f;
        #pragma unroll 4
        for (int i = 0; i < 32; ++i) {
            int ph = (i + rot2) & 31;
            float4 cA = ch[chA + ph];
            float4 cB = ch[chB + ph];
            float2 w = wvl[i*16 + o];
            vsA += cA.w*w.x; uA0 += cA.x*w.y; uA1 += cA.y*w.y; uA2 += cA.z*w.y;
            vsB += cB.w*w.x; uB0 += cB.x*w.y; uB1 += cB.y*w.y; uB2 += cB.z*w.y;
        }
        float lA = afeat[(mA*8 + h)*17 + 16];
        float lB = afeat[(mB*8 + h)*17 + 16];
        float Mg = mred[h];
        float wgA = expf(lA - Mg);   // masked: exp(-huge)=0; all-masked group:
        float wgB = expf(lB - Mg);   //   Mg=NEGMAX -> zeroed later by exp(Mg-M*)
        w4[s*128 + c] = make_float4(wgA*uA0 + wgB*uB0, wgA*uA1 + wgB*uB1,
                                    wgA*uA2 + wgB*uB2, wgA*vsA + wgB*vsB);
    }
    __syncthreads();

    // tail: combine 4 s-slots -> one partial float4 per channel; emit Mg/deng
    if (t < 128) {
        float4 a = w4[t], b4 = w4[128 + t], c4 = w4[256 + t], d4 = w4[384 + t];
        pbuf[((size_t)(n*4 + g))*D_F + t] =
            make_float4(a.x + b4.x + c4.x + d4.x, a.y + b4.y + c4.y + d4.y,
                        a.z + b4.z + c4.z + d4.z, a.w + b4.w + c4.w + d4.w);
    } else if (t < 144) {
        mbuf[(n*4 + g)*16 + (t - 128)] = mred[t - 128];
    }
}

// ---------------------------------------------------------------------------
// k_finish: combine 4 flash partials, softmax probs from raw logits,
// Wo linear + skip add.
// ---------------------------------------------------------------------------
__global__ __launch_bounds__(128) void k_finish(
    const float4* __restrict__ pbuf, const float* __restrict__ mbuf,
    float* __restrict__ attn_out,     // in: raw logits, out: probabilities
    const float* __restrict__ skip_s, const float* __restrict__ skip_v,
    const float* __restrict__ WoP, const float* __restrict__ bo,
    float* __restrict__ out0, float* __restrict__ out1)
{
    const int n = blockIdx.x, t = threadIdx.x;
    __shared__ float Ms[H_N], Dn[H_N];
    __shared__ float4 xsh[D_F];
    if (t < 32) {
        int h3 = t >> 2, g3 = t & 3;
        float mg = mbuf[(n*4 + g3)*16 + h3];
        float dg = mbuf[(n*4 + g3)*16 + 8 + h3];
        float mx = mg;
        mx = fmaxf(mx, __shfl_xor(mx, 1));
        mx = fmaxf(mx, __shfl_xor(mx, 2));
        float dsc = dg * expf(mg - mx);   // all-masked group: exp(NEG-M)=0
        dsc += __shfl_xor(dsc, 1);
        dsc += __shfl_xor(dsc, 2);
        if (g3 == 0) { Ms[h3] = mx; Dn[h3] = dsc; }
    }
    __syncthreads();
    const int h = t >> 4, o = t & 15;
    const float M = Ms[h];
    const float rden = 1.f / Dn[h];
    float4 acc = make_float4(0.f, 0.f, 0.f, 0.f);
    #pragma unroll
    for (int gg = 0; gg < 4; ++gg) {
        float4 pv = pbuf[((size_t)(n*4 + gg))*D_F + t];
        float sf = expf(mbuf[(n*4 + gg)*16 + h] - M) * rden;
        acc.x += pv.x*sf; acc.y += pv.y*sf; acc.z += pv.z*sf; acc.w += pv.w*sf;
    }
    xsh[t] = acc;
    #pragma unroll
    for (int kk = 0; kk < 2; ++kk) {
        size_t idx = (size_t)h*(N_Q*K_E) + (size_t)n*K_E + (o + kk*16);
        attn_out[idx] = expf(attn_out[idx] - M) * rden;
    }
    __syncthreads();
    const float2* wp = ((const float2*)WoP) + (size_t)t*128;
    float acc_s = bo[t], o0 = 0.f, o1 = 0.f, o2 = 0.f;
    #pragma unroll 4
    for (int i = 0; i < D_F; ++i) {
        float4 x = xsh[i];
        float2 w = wp[i];
        acc_s += x.w*w.x; o0 += x.x*w.y; o1 += x.y*w.y; o2 += x.z*w.y;
    }
    out0[n*D_F + t] = acc_s + skip_s[n*D_F + t];
    out1[(n*D_F + t)*3 + 0] = o0 + skip_v[(n*D_F + t)*3 + 0];
    out1[(n*D_F + t)*3 + 1] = o1 + skip_v[(n*D_F + t)*3 + 1];
    out1[(n*D_F + t)*3 + 2] = o2 + skip_v[(n*D_F + t)*3 + 2];
}

// ---------------------------------------------------------------------------
extern "C" void kernel_launch(void* const* d_in, const int* in_sizes, int n_in,
                              void* d_out, int out_size, void* d_ws, size_t ws_size,
                              hipStream_t stream)
{
    (void)in_sizes; (void)n_in; (void)out_size; (void)ws_size;

    const float* query_s = (const float*)d_in[0];
    const float* query_v = (const float*)d_in[1];
    const float* key_s   = (const float*)d_in[2];
    const float* key_v   = (const float*)d_in[3];
    const float* eis     = (const float*)d_in[4];
    const float* eiv     = (const float*)d_in[5];
    const float* eemb    = (const float*)d_in[6];
    const int*   mask    = (const int*)d_in[7];
    const int*   knn     = (const int*)d_in[8];
    const float* Wq_s    = (const float*)d_in[9];
    const float* Wq_v    = (const float*)d_in[10];
    const float* bq      = (const float*)d_in[11];
    const float* Wk_s    = (const float*)d_in[12];
    const float* Wk_v    = (const float*)d_in[13];
    const float* bk      = (const float*)d_in[14];
    const float* Wqk_s   = (const float*)d_in[15];
    const float* Wqk_v   = (const float*)d_in[16];
    const float* bqk     = (const float*)d_in[17];
    const float* Wdtp    = (const float*)d_in[18];
    const float* bdtp    = (const float*)d_in[19];
    const float* Wagv_s  = (const float*)d_in[20];
    const float* bagv    = (const float*)d_in[21];
    const float* Wagv_v  = (const float*)d_in[22];
    const float* Wattn   = (const float*)d_in[23];
    const float* Wval_s  = (const float*)d_in[24];
    const float* Wval_v  = (const float*)d_in[25];
    const float* bval    = (const float*)d_in[26];
    const float* Wo_s    = (const float*)d_in[27];
    const float* Wo_v    = (const float*)d_in[28];
    const float* bo      = (const float*)d_in[29];
    const float* ln_gs   = (const float*)d_in[30];
    const float* ln_bs   = (const float*)d_in[31];
    const float* ln_gv   = (const float*)d_in[32];
    const float* lna_g   = (const float*)d_in[33];
    const float* lna_b   = (const float*)d_in[34];

    float* out      = (float*)d_out;
    float* out_s    = out;
    float* out_v    = out + N_Q*D_F;
    float* out_attn = out + N_Q*D_F*4;

    float* ws = (float*)d_ws;
    float4* q4     = (float4*)ws;                      // N*128 f4 = 4 MB
    float4* k4     = q4 + N_Q*D_F;                     // 4 MB
    float*  skip_s = (float*)(k4 + N_Q*D_F);           // 1 MB
    float*  skip_v = skip_s + N_Q*D_F;                 // 3 MB
    float4* pbuf   = (float4*)(skip_v + N_Q*D_F*3);    // N*4*128 f4 = 16 MB
    float*  mbuf   = (float*)(pbuf + N_Q*4*D_F);       // N*4*16 f = 512 KB
    float*  wpk    = mbuf + N_Q*4*16;                  // 280576 f ~ 1.1 MB

    float* WdtpT = wpk;
    float* WqP   = wpk + 65536;
    float* WkP   = wpk + 131072;
    float* WoP   = wpk + 196608;
    float* wqk2  = wpk + 262144;
    float* wagv4 = wpk + 263168;
    float* wval2 = wpk + 279552;

    hipLaunchKernelGGL(k_packw, dim3(1096), dim3(256), 0, stream,
                       Wdtp, Wq_s, Wq_v, Wk_s, Wk_v, Wo_s, Wo_v,
                       Wqk_s, Wqk_v, Wagv_s, Wagv_v, Wval_s, Wval_v, wpk);
    hipLaunchKernelGGL(k_qk, dim3(2*N_Q), dim3(D_F), 0, stream,
                       query_s, query_v, key_s, key_v,
                       WqP, bq, WkP, bk,
                       ln_gs, ln_bs, ln_gv,
                       q4, k4, skip_s, skip_v);
    hipLaunchKernelGGL(k_edge_flash, dim3(N_Q*K_E/EPB), dim3(512), 0, stream,
                       q4, k4, eis, eiv, eemb, mask, knn,
                       wqk2, bqk, WdtpT, bdtp,
                       wagv4, bagv, Wattn, lna_g, lna_b,
                       wval2, bval,
                       pbuf, mbuf, out_attn);
    hipLaunchKernelGGL(k_finish, dim3(N_Q), dim3(D_F), 0, stream,
                       pbuf, mbuf, out_attn, skip_s, skip_v, WoP, bo,
                       out_s, out_v);
}

// Round 7
// 557.682 us; speedup vs baseline: 1.3117x; 1.3117x over previous
//
#include <hip/hip_runtime.h>
#include <hip/hip_bf16.h>
#include <math.h>

#define N_Q 2048
#define K_E 32
#define D_F 128
#define H_N 8
#define DH_N 16
#define EPS_F 1e-5f
#define NEGMAX -3.4028235e38f
#define EPB 8      // edges per edge-block

// R18: R3 (best passing, 560us) + mask compaction. ~50% of edges are masked
// and contribute EXACT zeros (softmax weight exp(NEGMAX-M)=0, prob 0).
// k_prep ballots the mask per n -> compacted kidx list + u count, prefills
// NEGMAX logits at masked positions and mbuf for dead groups. Edge blocks
// process compacted slots; blocks with g*8 >= u return immediately (~37% of
// 8192). Invalid tail slots clamp to a valid edge, killed by logit=NEGMAX
// (exact 0 weight), attn_raw write suppressed. k_finish guards dead groups.
// R17's weight repacking REVERTED (destroyed inter-lane coalescing, -140us).

// ---------------------------------------------------------------------------
// k_prep: one wave per n. Ballot-compact unmasked k's; prefill masked logits
// with NEGMAX; prefill mbuf (Mg=NEGMAX, den=0) for dead groups.
// ---------------------------------------------------------------------------
__global__ __launch_bounds__(64) void k_prep(
    const int* __restrict__ mask, int* __restrict__ kidx, int* __restrict__ ucnt,
    float* __restrict__ attn_raw, float* __restrict__ mbuf)
{
    const int n = blockIdx.x, t = threadIdx.x;
    const int k = t & 31;
    int mk = (t < 32) ? mask[n*K_E + k] : 0;
    unsigned long long bal = __ballot(mk != 0);
    int u = (int)__popcll(bal);
    if (t < 32 && mk) {
        int pos = (int)__popcll(bal & ((1ull << k) - 1ull));
        kidx[n*K_E + pos] = k;
    }
    if (t == 0) ucnt[n] = u;
    // NEGMAX prefill for masked logits: lanes 0-31 cover h=0..3, 32-63 h=4..7
    if (mask[n*K_E + k] == 0) {
        int hb = (t >> 5) * 4;
        #pragma unroll
        for (int hh = 0; hh < 4; ++hh)
            attn_raw[(size_t)(hb + hh)*(N_Q*K_E) + n*K_E + k] = NEGMAX;
    }
    // dead-group mbuf prefill
    int gU = (u + 7) >> 3;
    if (t < 16) {
        for (int g2 = gU; g2 < 4; ++g2)
            mbuf[(n*4 + g2)*16 + t] = (t < 8) ? NEGMAX : 0.f;
    }
}

// ---------------------------------------------------------------------------
// Kernel A+B: query LN+Wq (blocks [0,N)) / key Wk (blocks [N,2N)).
// Outputs packed float4: .xyz = vector part, .w = scalar part.
// ---------------------------------------------------------------------------
__global__ __launch_bounds__(128) void k_qk(
    const float* __restrict__ qs_in, const float* __restrict__ qv_in,
    const float* __restrict__ ks_in, const float* __restrict__ kv_in,
    const float* __restrict__ Wq_s, const float* __restrict__ Wq_v, const float* __restrict__ bq,
    const float* __restrict__ Wk_s, const float* __restrict__ Wk_v, const float* __restrict__ bk,
    const float* __restrict__ ln_gs, const float* __restrict__ ln_bs, const float* __restrict__ ln_gv,
    float4* __restrict__ q4, float4* __restrict__ k4,
    float* __restrict__ skip_s, float* __restrict__ skip_v)
{
    const int t = threadIdx.x;
    __shared__ __align__(16) float raw[D_F*3];
    __shared__ float4 sv[D_F];
    __shared__ float red[6];
    if (blockIdx.x < N_Q) {
        const int n = blockIdx.x;
        float sval = qs_in[n*D_F + t];
        float ssqp = 0.f;
        if (t < 96) {
            float4 rv = ((const float4*)(qv_in + (size_t)n*D_F*3))[t];
            ((float4*)raw)[t] = rv;
            ssqp = rv.x*rv.x + rv.y*rv.y + rv.z*rv.z + rv.w*rv.w;
        }
        float r0 = sval, r1 = sval*sval, r2 = ssqp;
        #pragma unroll
        for (int m = 1; m < 64; m <<= 1) {
            r0 += __shfl_xor(r0, m);
            r1 += __shfl_xor(r1, m);
            r2 += __shfl_xor(r2, m);
        }
        if ((t & 63) == 0) { int w = t >> 6; red[w*3+0]=r0; red[w*3+1]=r1; red[w*3+2]=r2; }
        __syncthreads();
        float tS = red[0]+red[3], tS2 = red[1]+red[4], tQ = red[2]+red[5];
        float mu = tS * (1.f/D_F);
        float var = fmaxf(tS2*(1.f/D_F) - mu*mu, 0.f);
        float rstd = rsqrtf(var + EPS_F);
        float rrms = rsqrtf(tQ*(1.f/D_F) + EPS_F);
        float a = (sval - mu)*rstd*ln_gs[t] + ln_bs[t];
        skip_s[n*D_F + t] = a;
        float gv = ln_gv[t];
        float b0 = raw[t*3+0]*rrms*gv;
        float b1 = raw[t*3+1]*rrms*gv;
        float b2 = raw[t*3+2]*rrms*gv;
        skip_v[(n*D_F + t)*3 + 0] = b0;
        skip_v[(n*D_F + t)*3 + 1] = b1;
        skip_v[(n*D_F + t)*3 + 2] = b2;
        sv[t] = make_float4(b0, b1, b2, a);
        __syncthreads();
        float acc = bq[t], a0 = 0.f, a1 = 0.f, a2 = 0.f;
        #pragma unroll 4
        for (int i = 0; i < D_F; ++i) {
            float4 p = sv[i];
            float ws = Wq_s[i*D_F + t];
            float wv = Wq_v[i*D_F + t];
            acc += p.w*ws; a0 += p.x*wv; a1 += p.y*wv; a2 += p.z*wv;
        }
        q4[n*D_F + t] = make_float4(a0, a1, a2, acc);
    } else {
        const int n = blockIdx.x - N_Q;
        float sval = ks_in[n*D_F + t];
        if (t < 96) ((float4*)raw)[t] = ((const float4*)(kv_in + (size_t)n*D_F*3))[t];
        __syncthreads();
        sv[t] = make_float4(raw[t*3+0], raw[t*3+1], raw[t*3+2], sval);
        __syncthreads();
        float acc = bk[t], a0 = 0.f, a1 = 0.f, a2 = 0.f;
        #pragma unroll 4
        for (int i = 0; i < D_F; ++i) {
            float4 p = sv[i];
            float ws = Wk_s[i*D_F + t];
            float wv = Wk_v[i*D_F + t];
            acc += p.w*ws; a0 += p.x*wv; a1 += p.y*wv; a2 += p.z*wv;
        }
        k4[n*D_F + t] = make_float4(a0, a1, a2, acc);
    }
}

// ---------------------------------------------------------------------------
// k_edge_flash: R3 pipeline on COMPACTED edge slots. Block (n,g) handles
// compacted slots g*8..g*8+7; dead blocks (g*8 >= u) return immediately.
// ---------------------------------------------------------------------------
__global__ __launch_bounds__(512, 6) void k_edge_flash(
    const float4* __restrict__ q4, const float4* __restrict__ k4,
    const float* __restrict__ eis, const float* __restrict__ eiv,
    const float* __restrict__ eemb,
    const int* __restrict__ knn,
    const int* __restrict__ kidx, const int* __restrict__ ucnt,
    const float* __restrict__ Wqk_s, const float* __restrict__ Wqk_v, const float* __restrict__ bqk,
    const float* __restrict__ Wdtp, const float* __restrict__ bdtp,
    const float* __restrict__ Wagv_s, const float* __restrict__ bagv, const float* __restrict__ Wagv_v,
    const float* __restrict__ Wattn, const float* __restrict__ lna_g, const float* __restrict__ lna_b,
    const float* __restrict__ Wval_s, const float* __restrict__ Wval_v, const float* __restrict__ bval,
    float4* __restrict__ pbuf, float* __restrict__ mbuf, float* __restrict__ attn_raw)
{
    const int n = blockIdx.x >> 2;
    const int g = blockIdx.x & 3;
    const int base = n*K_E;
    const int u = ucnt[n];
    if ((g << 3) >= u) return;         // dead group: mbuf prefilled by k_prep

    const int t = threadIdx.x;
    const int s = t >> 7, c = t & 127, h = (t >> 4) & 7, o = t & 15;
    const int rot2 = h * 2;

    __shared__ float4 ch[EPB*256];     // 32 KB (stage-A ee aliased here)
    __shared__ float4 w4[EPB*128];     // 16 KB; reused as partial-combine stage
    __shared__ float  afeat[EPB*8*17]; // 4.25 KB: 16 feats + logit col 16
    __shared__ float  mred[16];        // Mg[8], deng[8]

    // stage A: ee gather (compacted, transposed, aliased into ch) + w GEMM
    {
        float* ee = (float*)ch;        // [128][8] floats = 4 KB
        {
            int idx = t; int m = idx & 7, i = idx >> 3;
            int jj = (g<<3) + m; jj = (jj < u) ? jj : (u-1);
            int e = base + kidx[base + jj];
            ee[i*EPB+m] = eemb[(size_t)e*D_F + i];
        }
        {
            int idx = t + 512; int m = idx & 7, i = idx >> 3;
            int jj = (g<<3) + m; jj = (jj < u) ? jj : (u-1);
            int e = base + kidx[base + jj];
            ee[i*EPB+m] = eemb[(size_t)e*D_F + i];
        }
        __syncthreads();
        float acc[EPB];
        float b = bdtp[t];
        #pragma unroll
        for (int m = 0; m < EPB; ++m) acc[m] = b;
        #pragma unroll 2
        for (int i = 0; i < D_F; ++i) {
            float wv = Wdtp[i*512 + t];
            #pragma unroll
            for (int m = 0; m < EPB; ++m) acc[m] += ee[i*EPB+m]*wv;
        }
        __syncthreads();               // all ee reads done -> ch reusable
        float* w4f = (float*)w4;
        const int chn = t & 127, sel = t >> 7;
        #pragma unroll
        for (int m = 0; m < EPB; ++m)
            w4f[(m*128 + chn)*4 + sel] = acc[m];
    }

    const int mA = s, mB = s + 4;
    int jA = (g<<3) + mA; jA = (jA < u) ? jA : (u-1);
    int jB = (g<<3) + mB; jB = (jB < u) ? jB : (u-1);
    const int eA = base + kidx[base + jA];
    const int eB = base + kidx[base + jB];

    const float esA = eis[eA], esB = eis[eB];
    const float evAx = eiv[eA*3+0], evAy = eiv[eA*3+1], evAz = eiv[eA*3+2];
    const float evBx = eiv[eB*3+0], evBy = eiv[eB*3+1], evBz = eiv[eB*3+2];

    // B1: dtp1 straight from global
    {
        float4 q  = q4[(size_t)n*D_F + c];
        float4 kA = k4[(size_t)knn[eA]*D_F + c];
        float4 kB = k4[(size_t)knn[eB]*D_F + c];
        const int hp = c >> 5, jc = c & 31;
        const int pos0 = hp*32 + ((jc + 2*hp) & 31);
        const int pos1 = (hp+4)*32 + ((jc + 2*(hp+4)) & 31);
        ch[mA*256 + pos0] = make_float4(q.w*kA.x, q.w*kA.y, q.w*kA.z, q.w*kA.w);
        ch[mA*256 + pos1] = make_float4(kA.w*q.x, kA.w*q.y, kA.w*q.z,
                                        q.x*kA.x + q.y*kA.y + q.z*kA.z);
        ch[mB*256 + pos0] = make_float4(q.w*kB.x, q.w*kB.y, q.w*kB.z, q.w*kB.w);
        ch[mB*256 + pos1] = make_float4(kB.w*q.x, kB.w*q.y, kB.w*q.z,
                                        q.x*kB.x + q.y*kB.y + q.z*kB.z);
    }
    __syncthreads();

    const int chA = mA*256 + h*32, chB = mB*256 + h*32;

    // B2: Wqk
    float pAs, pA0, pA1, pA2, pBs, pB0, pB1, pB2;
    {
        const float bqk_r = bqk[o];
        pAs = bqk_r; pA0 = 0.f; pA1 = 0.f; pA2 = 0.f;
        pBs = bqk_r; pB0 = 0.f; pB1 = 0.f; pB2 = 0.f;
        #pragma unroll 4
        for (int i = 0; i < 32; ++i) {
            int ph = (i + rot2) & 31;
            float4 cA = ch[chA + ph];
            float4 cB = ch[chB + ph];
            float ws = Wqk_s[i*16 + o];
            float wv = Wqk_v[i*16 + o];
            pAs += cA.w*ws; pA0 += cA.x*wv; pA1 += cA.y*wv; pA2 += cA.z*wv;
            pBs += cB.w*ws; pB0 += cB.x*wv; pB1 += cB.y*wv; pB2 += cB.z*wv;
        }
    }
    __syncthreads();

    const int posA = h*32 + ((o + rot2) & 31);
    const int posB = h*32 + ((o + 16 + rot2) & 31);

    // B3: dtp2 (weighted)
    {
        float4 wA = w4[mA*128 + c];
        float4 wB = w4[mB*128 + c];
        ch[mA*256 + posA] = make_float4(pAs*evAx*wA.z, pAs*evAy*wA.z, pAs*evAz*wA.z, pAs*esA*wA.x);
        float dA = pA0*evAx + pA1*evAy + pA2*evAz;
        ch[mA*256 + posB] = make_float4(esA*pA0*wA.w, esA*pA1*wA.w, esA*pA2*wA.w, dA*wA.y);
        ch[mB*256 + posA] = make_float4(pBs*evBx*wB.z, pBs*evBy*wB.z, pBs*evBz*wB.z, pBs*esB*wB.x);
        float dB = pB0*evBx + pB1*evBy + pB2*evBz;
        ch[mB*256 + posB] = make_float4(esB*pB0*wB.w, esB*pB1*wB.w, esB*pB2*wB.w, dB*wB.y);
    }
    __syncthreads();

    // B4: Wagv
    float gtA, vlA, vA0, vA1, vA2, gtB, vlB, vB0, vB1, vB2;
    {
        const float bag0 = bagv[h*48 + o];
        const float bag1 = bagv[h*48 + 16 + o];
        const float bag2 = bagv[h*48 + 32 + o];
        float atA = bag0, atB = bag0;
        gtA = bag1; vlA = bag2; vA0 = 0.f; vA1 = 0.f; vA2 = 0.f;
        gtB = bag1; vlB = bag2; vB0 = 0.f; vB1 = 0.f; vB2 = 0.f;
        #pragma unroll 4
        for (int i = 0; i < 32; ++i) {
            int ph = (i + rot2) & 31;
            float4 cA = ch[chA + ph];
            float4 cB = ch[chB + ph];
            const float* wrow = &Wagv_s[(h*32+i)*48];
            float w0 = wrow[o], w1 = wrow[16+o], w2 = wrow[32+o];
            float wv = Wagv_v[(h*32+i)*16 + o];
            atA += cA.w*w0; gtA += cA.w*w1; vlA += cA.w*w2;
            vA0 += cA.x*wv; vA1 += cA.y*wv; vA2 += cA.z*wv;
            atB += cB.w*w0; gtB += cB.w*w1; vlB += cB.w*w2;
            vB0 += cB.x*wv; vB1 += cB.y*wv; vB2 += cB.z*wv;
        }
        afeat[(mA*8 + h)*17 + o] = atA;
        afeat[(mB*8 + h)*17 + o] = atB;
    }
    __syncthreads();

    // B5: logits (wave 0: 8 slots x 8 heads) + group max/den via shuffles
    if (t < EPB*H_N) {
        int m2 = t >> 3, h2 = t & 7;
        const float* afr = &afeat[(m2*8 + h2)*17];
        float mu = 0.f;
        #pragma unroll 4
        for (int d2 = 0; d2 < DH_N; ++d2) mu += afr[d2];
        mu *= (1.f/DH_N);
        float var = 0.f;
        #pragma unroll 4
        for (int d2 = 0; d2 < DH_N; ++d2) { float dd = afr[d2]-mu; var += dd*dd; }
        var *= (1.f/DH_N);
        float rstd = rsqrtf(var + EPS_F);
        float logit = 0.f;
        #pragma unroll 4
        for (int d2 = 0; d2 < DH_N; ++d2) {
            float xn = (afr[d2]-mu)*rstd*lna_g[d2] + lna_b[d2];
            logit += xn*Wattn[d2];
        }
        int jj = (g<<3) + m2;
        bool vok = jj < u;
        if (vok) {
            int kor = kidx[base + jj];
            attn_raw[h2*(N_Q*K_E) + n*K_E + kor] = logit;
        } else {
            logit = NEGMAX;            // clamped duplicate slot: exact 0 weight
        }
        afeat[(m2*8 + h2)*17 + 16] = logit;
        float mx = logit;
        mx = fmaxf(mx, __shfl_xor(mx, 8));
        mx = fmaxf(mx, __shfl_xor(mx, 16));
        mx = fmaxf(mx, __shfl_xor(mx, 32));
        float ex = expf(logit - mx);
        ex += __shfl_xor(ex, 8);
        ex += __shfl_xor(ex, 16);
        ex += __shfl_xor(ex, 32);
        if (m2 == 0) { mred[h2] = mx; mred[8 + h2] = ex; }
    }
    // gating (register-only, all threads)
    float sactA = vlA / (1.f + expf(-vlA));
    float gA = 1.f / (1.f + expf(-gtA));
    float qA0 = vA0*gA, qA1 = vA1*gA, qA2 = vA2*gA;
    float sactB = vlB / (1.f + expf(-vlB));
    float gB = 1.f / (1.f + expf(-gtB));
    float qB0 = vB0*gB, qB1 = vB1*gB, qB2 = vB2*gB;

    // B6: dtp3
    {
        ch[mA*256 + posA] = make_float4(sactA*evAx, sactA*evAy, sactA*evAz, sactA*esA);
        float dA = qA0*evAx + qA1*evAy + qA2*evAz;
        ch[mA*256 + posB] = make_float4(esA*qA0, esA*qA1, esA*qA2, dA);
        ch[mB*256 + posA] = make_float4(sactB*evBx, sactB*evBy, sactB*evBz, sactB*esB);
        float dB = qB0*evBx + qB1*evBy + qB2*evBz;
        ch[mB*256 + posB] = make_float4(esB*qB0, esB*qB1, esB*qB2, dB);
    }
    __syncthreads();

    // B7: Wval -> registers, weight by exp(logit - Mg), stage partial in w4
    {
        const float bval_r = bval[o];
        float vsA = bval_r, uA0 = 0.f, uA1 = 0.f, uA2 = 0.f;
        float vsB = bval_r, uB0 = 0.f, uB1 = 0.f, uB2 = 0.f;
        #pragma unroll 4
        for (int i = 0; i < 32; ++i) {
            int ph = (i + rot2) & 31;
            float4 cA = ch[chA + ph];
            float4 cB = ch[chB + ph];
            float ws = Wval_s[i*16 + o];
            float wv = Wval_v[i*16 + o];
            vsA += cA.w*ws; uA0 += cA.x*wv; uA1 += cA.y*wv; uA2 += cA.z*wv;
            vsB += cB.w*ws; uB0 += cB.x*wv; uB1 += cB.y*wv; uB2 += cB.z*wv;
        }
        float lA = afeat[(mA*8 + h)*17 + 16];
        float lB = afeat[(mB*8 + h)*17 + 16];
        float Mg = mred[h];
        float wgA = expf(lA - Mg);     // invalid slot: exp(-inf)=0 exact
        float wgB = expf(lB - Mg);
        w4[s*128 + c] = make_float4(wgA*uA0 + wgB*uB0, wgA*uA1 + wgB*uB1,
                                    wgA*uA2 + wgB*uB2, wgA*vsA + wgB*vsB);
    }
    __syncthreads();

    // tail: combine 4 s-slots -> one partial float4 per channel; emit Mg/deng
    if (t < 128) {
        float4 a = w4[t], b4 = w4[128 + t], c4 = w4[256 + t], d4 = w4[384 + t];
        pbuf[((size_t)(n*4 + g))*D_F + t] =
            make_float4(a.x + b4.x + c4.x + d4.x, a.y + b4.y + c4.y + d4.y,
                        a.z + b4.z + c4.z + d4.z, a.w + b4.w + c4.w + d4.w);
    } else if (t < 144) {
        mbuf[(n*4 + g)*16 + (t - 128)] = mred[t - 128];
    }
}

// ---------------------------------------------------------------------------
// k_finish: combine active flash partials, softmax probs from raw logits,
// Wo linear + skip add.
// ---------------------------------------------------------------------------
__global__ __launch_bounds__(128) void k_finish(
    const float4* __restrict__ pbuf, const float* __restrict__ mbuf,
    float* __restrict__ attn_out,     // in: raw logits, out: probabilities
    const float* __restrict__ skip_s, const float* __restrict__ skip_v,
    const float* __restrict__ Wo_s, const float* __restrict__ Wo_v, const float* __restrict__ bo,
    float* __restrict__ out0, float* __restrict__ out1)
{
    const int n = blockIdx.x, t = threadIdx.x;
    __shared__ float Ms[H_N], Dn[H_N];
    __shared__ float4 xsh[D_F];
    if (t < 32) {
        int h3 = t >> 2, g3 = t & 3;
        float mg = mbuf[(n*4 + g3)*16 + h3];
        float dg = mbuf[(n*4 + g3)*16 + 8 + h3];
        float mx = mg;
        mx = fmaxf(mx, __shfl_xor(mx, 1));
        mx = fmaxf(mx, __shfl_xor(mx, 2));
        float dsc = dg * expf(mg - mx);   // dead group: 0 * 0
        dsc += __shfl_xor(dsc, 1);
        dsc += __shfl_xor(dsc, 2);
        if (g3 == 0) { Ms[h3] = mx; Dn[h3] = dsc; }
    }
    __syncthreads();
    const int h = t >> 4, o = t & 15;
    const float M = Ms[h];
    const float rden = 1.f / Dn[h];
    float4 acc = make_float4(0.f, 0.f, 0.f, 0.f);
    #pragma unroll
    for (int gg = 0; gg < 4; ++gg) {
        float mg = mbuf[(n*4 + gg)*16 + h];
        if (mg > -1e37f) {             // skip dead groups (pbuf unwritten)
            float4 pv = pbuf[((size_t)(n*4 + gg))*D_F + t];
            float sf = expf(mg - M) * rden;
            acc.x += pv.x*sf; acc.y += pv.y*sf; acc.z += pv.z*sf; acc.w += pv.w*sf;
        }
    }
    xsh[t] = acc;
    #pragma unroll
    for (int kk = 0; kk < 2; ++kk) {
        size_t idx = (size_t)h*(N_Q*K_E) + (size_t)n*K_E + (o + kk*16);
        attn_out[idx] = expf(attn_out[idx] - M) * rden;
    }
    __syncthreads();
    float acc_s = bo[t], o0 = 0.f, o1 = 0.f, o2 = 0.f;
    #pragma unroll 4
    for (int i = 0; i < D_F; ++i) {
        float4 x = xsh[i];
        float ws = Wo_s[i*D_F + t];
        float wv = Wo_v[i*D_F + t];
        acc_s += x.w*ws; o0 += x.x*wv; o1 += x.y*wv; o2 += x.z*wv;
    }
    out0[n*D_F + t] = acc_s + skip_s[n*D_F + t];
    out1[(n*D_F + t)*3 + 0] = o0 + skip_v[(n*D_F + t)*3 + 0];
    out1[(n*D_F + t)*3 + 1] = o1 + skip_v[(n*D_F + t)*3 + 1];
    out1[(n*D_F + t)*3 + 2] = o2 + skip_v[(n*D_F + t)*3 + 2];
}

// ---------------------------------------------------------------------------
extern "C" void kernel_launch(void* const* d_in, const int* in_sizes, int n_in,
                              void* d_out, int out_size, void* d_ws, size_t ws_size,
                              hipStream_t stream)
{
    (void)in_sizes; (void)n_in; (void)out_size; (void)ws_size;

    const float* query_s = (const float*)d_in[0];
    const float* query_v = (const float*)d_in[1];
    const float* key_s   = (const float*)d_in[2];
    const float* key_v   = (const float*)d_in[3];
    const float* eis     = (const float*)d_in[4];
    const float* eiv     = (const float*)d_in[5];
    const float* eemb    = (const float*)d_in[6];
    const int*   mask    = (const int*)d_in[7];
    const int*   knn     = (const int*)d_in[8];
    const float* Wq_s    = (const float*)d_in[9];
    const float* Wq_v    = (const float*)d_in[10];
    const float* bq      = (const float*)d_in[11];
    const float* Wk_s    = (const float*)d_in[12];
    const float* Wk_v    = (const float*)d_in[13];
    const float* bk      = (const float*)d_in[14];
    const float* Wqk_s   = (const float*)d_in[15];
    const float* Wqk_v   = (const float*)d_in[16];
    const float* bqk     = (const float*)d_in[17];
    const float* Wdtp    = (const float*)d_in[18];
    const float* bdtp    = (const float*)d_in[19];
    const float* Wagv_s  = (const float*)d_in[20];
    const float* bagv    = (const float*)d_in[21];
    const float* Wagv_v  = (const float*)d_in[22];
    const float* Wattn   = (const float*)d_in[23];
    const float* Wval_s  = (const float*)d_in[24];
    const float* Wval_v  = (const float*)d_in[25];
    const float* bval    = (const float*)d_in[26];
    const float* Wo_s    = (const float*)d_in[27];
    const float* Wo_v    = (const float*)d_in[28];
    const float* bo      = (const float*)d_in[29];
    const float* ln_gs   = (const float*)d_in[30];
    const float* ln_bs   = (const float*)d_in[31];
    const float* ln_gv   = (const float*)d_in[32];
    const float* lna_g   = (const float*)d_in[33];
    const float* lna_b   = (const float*)d_in[34];

    float* out      = (float*)d_out;
    float* out_s    = out;
    float* out_v    = out + N_Q*D_F;
    float* out_attn = out + N_Q*D_F*4;

    float* ws = (float*)d_ws;
    float4* q4     = (float4*)ws;                      // N*128 f4 = 4 MB
    float4* k4     = q4 + N_Q*D_F;                     // 4 MB
    float*  skip_s = (float*)(k4 + N_Q*D_F);           // 1 MB
    float*  skip_v = skip_s + N_Q*D_F;                 // 3 MB
    float4* pbuf   = (float4*)(skip_v + N_Q*D_F*3);    // N*4*128 f4 = 16 MB
    float*  mbuf   = (float*)(pbuf + N_Q*4*D_F);       // N*4*16 f = 512 KB
    int*    kidx   = (int*)(mbuf + N_Q*4*16);          // N*K ints = 256 KB
    int*    ucnt   = kidx + N_Q*K_E;                   // N ints

    hipLaunchKernelGGL(k_prep, dim3(N_Q), dim3(64), 0, stream,
                       mask, kidx, ucnt, out_attn, mbuf);
    hipLaunchKernelGGL(k_qk, dim3(2*N_Q), dim3(D_F), 0, stream,
                       query_s, query_v, key_s, key_v,
                       Wq_s, Wq_v, bq, Wk_s, Wk_v, bk,
                       ln_gs, ln_bs, ln_gv,
                       q4, k4, skip_s, skip_v);
    hipLaunchKernelGGL(k_edge_flash, dim3(N_Q*K_E/EPB), dim3(512), 0, stream,
                       q4, k4, eis, eiv, eemb, knn, kidx, ucnt,
                       Wqk_s, Wqk_v, bqk, Wdtp, bdtp,
                       Wagv_s, bagv, Wagv_v, Wattn, lna_g, lna_b,
                       Wval_s, Wval_v, bval,
                       pbuf, mbuf, out_attn);
    hipLaunchKernelGGL(k_finish, dim3(N_Q), dim3(D_F), 0, stream,
                       pbuf, mbuf, out_attn, skip_s, skip_v, Wo_s, Wo_v, bo,
                       out_s, out_v);
}

// Round 8
// 436.379 us; speedup vs baseline: 1.6764x; 1.2780x over previous
//
#include <hip/hip_runtime.h>
#include <hip/hip_bf16.h>
#include <math.h>

#define N_Q 2048
#define K_E 32
#define D_F 128
#define H_N 8
#define DH_N 16
#define EPS_F 1e-5f
#define NEGMAX -3.4028235e38f
#define EPB 8      // edges per edge-block

// R19: R18 + g-major block mapping. R18's dead blocks aliased with the XCD
// round-robin (blockIdx%8): n-major order put g=3 (always dead) on XCDs 3/7,
// g=2 (half dead) on XCDs 2/6, and left XCDs 0,1,4,5 with the SAME 1024
// active blocks as R3 -> zero speedup, occupancy 36% (predicted 40% by the
// aliasing model). g-major (n = bid&2047, g = bid>>11) spreads dead blocks
// uniformly: per-XCD active load 1024 -> ~640. Also: all 4 groups of an n
// now share an XCD -> q4/k4 L2 reuse. Rest byte-identical to R18 (passing).

// ---------------------------------------------------------------------------
// k_prep: one wave per n. Ballot-compact unmasked k's; prefill masked logits
// with NEGMAX; prefill mbuf (Mg=NEGMAX, den=0) for dead groups.
// ---------------------------------------------------------------------------
__global__ __launch_bounds__(64) void k_prep(
    const int* __restrict__ mask, int* __restrict__ kidx, int* __restrict__ ucnt,
    float* __restrict__ attn_raw, float* __restrict__ mbuf)
{
    const int n = blockIdx.x, t = threadIdx.x;
    const int k = t & 31;
    int mk = (t < 32) ? mask[n*K_E + k] : 0;
    unsigned long long bal = __ballot(mk != 0);
    int u = (int)__popcll(bal);
    if (t < 32 && mk) {
        int pos = (int)__popcll(bal & ((1ull << k) - 1ull));
        kidx[n*K_E + pos] = k;
    }
    if (t == 0) ucnt[n] = u;
    // NEGMAX prefill for masked logits: lanes 0-31 cover h=0..3, 32-63 h=4..7
    if (mask[n*K_E + k] == 0) {
        int hb = (t >> 5) * 4;
        #pragma unroll
        for (int hh = 0; hh < 4; ++hh)
            attn_raw[(size_t)(hb + hh)*(N_Q*K_E) + n*K_E + k] = NEGMAX;
    }
    // dead-group mbuf prefill
    int gU = (u + 7) >> 3;
    if (t < 16) {
        for (int g2 = gU; g2 < 4; ++g2)
            mbuf[(n*4 + g2)*16 + t] = (t < 8) ? NEGMAX : 0.f;
    }
}

// ---------------------------------------------------------------------------
// Kernel A+B: query LN+Wq (blocks [0,N)) / key Wk (blocks [N,2N)).
// Outputs packed float4: .xyz = vector part, .w = scalar part.
// ---------------------------------------------------------------------------
__global__ __launch_bounds__(128) void k_qk(
    const float* __restrict__ qs_in, const float* __restrict__ qv_in,
    const float* __restrict__ ks_in, const float* __restrict__ kv_in,
    const float* __restrict__ Wq_s, const float* __restrict__ Wq_v, const float* __restrict__ bq,
    const float* __restrict__ Wk_s, const float* __restrict__ Wk_v, const float* __restrict__ bk,
    const float* __restrict__ ln_gs, const float* __restrict__ ln_bs, const float* __restrict__ ln_gv,
    float4* __restrict__ q4, float4* __restrict__ k4,
    float* __restrict__ skip_s, float* __restrict__ skip_v)
{
    const int t = threadIdx.x;
    __shared__ __align__(16) float raw[D_F*3];
    __shared__ float4 sv[D_F];
    __shared__ float red[6];
    if (blockIdx.x < N_Q) {
        const int n = blockIdx.x;
        float sval = qs_in[n*D_F + t];
        float ssqp = 0.f;
        if (t < 96) {
            float4 rv = ((const float4*)(qv_in + (size_t)n*D_F*3))[t];
            ((float4*)raw)[t] = rv;
            ssqp = rv.x*rv.x + rv.y*rv.y + rv.z*rv.z + rv.w*rv.w;
        }
        float r0 = sval, r1 = sval*sval, r2 = ssqp;
        #pragma unroll
        for (int m = 1; m < 64; m <<= 1) {
            r0 += __shfl_xor(r0, m);
            r1 += __shfl_xor(r1, m);
            r2 += __shfl_xor(r2, m);
        }
        if ((t & 63) == 0) { int w = t >> 6; red[w*3+0]=r0; red[w*3+1]=r1; red[w*3+2]=r2; }
        __syncthreads();
        float tS = red[0]+red[3], tS2 = red[1]+red[4], tQ = red[2]+red[5];
        float mu = tS * (1.f/D_F);
        float var = fmaxf(tS2*(1.f/D_F) - mu*mu, 0.f);
        float rstd = rsqrtf(var + EPS_F);
        float rrms = rsqrtf(tQ*(1.f/D_F) + EPS_F);
        float a = (sval - mu)*rstd*ln_gs[t] + ln_bs[t];
        skip_s[n*D_F + t] = a;
        float gv = ln_gv[t];
        float b0 = raw[t*3+0]*rrms*gv;
        float b1 = raw[t*3+1]*rrms*gv;
        float b2 = raw[t*3+2]*rrms*gv;
        skip_v[(n*D_F + t)*3 + 0] = b0;
        skip_v[(n*D_F + t)*3 + 1] = b1;
        skip_v[(n*D_F + t)*3 + 2] = b2;
        sv[t] = make_float4(b0, b1, b2, a);
        __syncthreads();
        float acc = bq[t], a0 = 0.f, a1 = 0.f, a2 = 0.f;
        #pragma unroll 4
        for (int i = 0; i < D_F; ++i) {
            float4 p = sv[i];
            float ws = Wq_s[i*D_F + t];
            float wv = Wq_v[i*D_F + t];
            acc += p.w*ws; a0 += p.x*wv; a1 += p.y*wv; a2 += p.z*wv;
        }
        q4[n*D_F + t] = make_float4(a0, a1, a2, acc);
    } else {
        const int n = blockIdx.x - N_Q;
        float sval = ks_in[n*D_F + t];
        if (t < 96) ((float4*)raw)[t] = ((const float4*)(kv_in + (size_t)n*D_F*3))[t];
        __syncthreads();
        sv[t] = make_float4(raw[t*3+0], raw[t*3+1], raw[t*3+2], sval);
        __syncthreads();
        float acc = bk[t], a0 = 0.f, a1 = 0.f, a2 = 0.f;
        #pragma unroll 4
        for (int i = 0; i < D_F; ++i) {
            float4 p = sv[i];
            float ws = Wk_s[i*D_F + t];
            float wv = Wk_v[i*D_F + t];
            acc += p.w*ws; a0 += p.x*wv; a1 += p.y*wv; a2 += p.z*wv;
        }
        k4[n*D_F + t] = make_float4(a0, a1, a2, acc);
    }
}

// ---------------------------------------------------------------------------
// k_edge_flash: R3 pipeline on COMPACTED edge slots, g-major block mapping.
// Block handles compacted slots g*8..g*8+7 of n; dead blocks return.
// ---------------------------------------------------------------------------
__global__ __launch_bounds__(512, 6) void k_edge_flash(
    const float4* __restrict__ q4, const float4* __restrict__ k4,
    const float* __restrict__ eis, const float* __restrict__ eiv,
    const float* __restrict__ eemb,
    const int* __restrict__ knn,
    const int* __restrict__ kidx, const int* __restrict__ ucnt,
    const float* __restrict__ Wqk_s, const float* __restrict__ Wqk_v, const float* __restrict__ bqk,
    const float* __restrict__ Wdtp, const float* __restrict__ bdtp,
    const float* __restrict__ Wagv_s, const float* __restrict__ bagv, const float* __restrict__ Wagv_v,
    const float* __restrict__ Wattn, const float* __restrict__ lna_g, const float* __restrict__ lna_b,
    const float* __restrict__ Wval_s, const float* __restrict__ Wval_v, const float* __restrict__ bval,
    float4* __restrict__ pbuf, float* __restrict__ mbuf, float* __restrict__ attn_raw)
{
    const int n = blockIdx.x & (N_Q - 1);   // g-major: XCD = n%8 per plane
    const int g = blockIdx.x >> 11;
    const int base = n*K_E;
    const int u = ucnt[n];
    if ((g << 3) >= u) return;         // dead group: mbuf prefilled by k_prep

    const int t = threadIdx.x;
    const int s = t >> 7, c = t & 127, h = (t >> 4) & 7, o = t & 15;
    const int rot2 = h * 2;

    __shared__ float4 ch[EPB*256];     // 32 KB (stage-A ee aliased here)
    __shared__ float4 w4[EPB*128];     // 16 KB; reused as partial-combine stage
    __shared__ float  afeat[EPB*8*17]; // 4.25 KB: 16 feats + logit col 16
    __shared__ float  mred[16];        // Mg[8], deng[8]

    // stage A: ee gather (compacted, transposed, aliased into ch) + w GEMM
    {
        float* ee = (float*)ch;        // [128][8] floats = 4 KB
        {
            int idx = t; int m = idx & 7, i = idx >> 3;
            int jj = (g<<3) + m; jj = (jj < u) ? jj : (u-1);
            int e = base + kidx[base + jj];
            ee[i*EPB+m] = eemb[(size_t)e*D_F + i];
        }
        {
            int idx = t + 512; int m = idx & 7, i = idx >> 3;
            int jj = (g<<3) + m; jj = (jj < u) ? jj : (u-1);
            int e = base + kidx[base + jj];
            ee[i*EPB+m] = eemb[(size_t)e*D_F + i];
        }
        __syncthreads();
        float acc[EPB];
        float b = bdtp[t];
        #pragma unroll
        for (int m = 0; m < EPB; ++m) acc[m] = b;
        #pragma unroll 2
        for (int i = 0; i < D_F; ++i) {
            float wv = Wdtp[i*512 + t];
            #pragma unroll
            for (int m = 0; m < EPB; ++m) acc[m] += ee[i*EPB+m]*wv;
        }
        __syncthreads();               // all ee reads done -> ch reusable
        float* w4f = (float*)w4;
        const int chn = t & 127, sel = t >> 7;
        #pragma unroll
        for (int m = 0; m < EPB; ++m)
            w4f[(m*128 + chn)*4 + sel] = acc[m];
    }

    const int mA = s, mB = s + 4;
    int jA = (g<<3) + mA; jA = (jA < u) ? jA : (u-1);
    int jB = (g<<3) + mB; jB = (jB < u) ? jB : (u-1);
    const int eA = base + kidx[base + jA];
    const int eB = base + kidx[base + jB];

    const float esA = eis[eA], esB = eis[eB];
    const float evAx = eiv[eA*3+0], evAy = eiv[eA*3+1], evAz = eiv[eA*3+2];
    const float evBx = eiv[eB*3+0], evBy = eiv[eB*3+1], evBz = eiv[eB*3+2];

    // B1: dtp1 straight from global
    {
        float4 q  = q4[(size_t)n*D_F + c];
        float4 kA = k4[(size_t)knn[eA]*D_F + c];
        float4 kB = k4[(size_t)knn[eB]*D_F + c];
        const int hp = c >> 5, jc = c & 31;
        const int pos0 = hp*32 + ((jc + 2*hp) & 31);
        const int pos1 = (hp+4)*32 + ((jc + 2*(hp+4)) & 31);
        ch[mA*256 + pos0] = make_float4(q.w*kA.x, q.w*kA.y, q.w*kA.z, q.w*kA.w);
        ch[mA*256 + pos1] = make_float4(kA.w*q.x, kA.w*q.y, kA.w*q.z,
                                        q.x*kA.x + q.y*kA.y + q.z*kA.z);
        ch[mB*256 + pos0] = make_float4(q.w*kB.x, q.w*kB.y, q.w*kB.z, q.w*kB.w);
        ch[mB*256 + pos1] = make_float4(kB.w*q.x, kB.w*q.y, kB.w*q.z,
                                        q.x*kB.x + q.y*kB.y + q.z*kB.z);
    }
    __syncthreads();

    const int chA = mA*256 + h*32, chB = mB*256 + h*32;

    // B2: Wqk
    float pAs, pA0, pA1, pA2, pBs, pB0, pB1, pB2;
    {
        const float bqk_r = bqk[o];
        pAs = bqk_r; pA0 = 0.f; pA1 = 0.f; pA2 = 0.f;
        pBs = bqk_r; pB0 = 0.f; pB1 = 0.f; pB2 = 0.f;
        #pragma unroll 4
        for (int i = 0; i < 32; ++i) {
            int ph = (i + rot2) & 31;
            float4 cA = ch[chA + ph];
            float4 cB = ch[chB + ph];
            float ws = Wqk_s[i*16 + o];
            float wv = Wqk_v[i*16 + o];
            pAs += cA.w*ws; pA0 += cA.x*wv; pA1 += cA.y*wv; pA2 += cA.z*wv;
            pBs += cB.w*ws; pB0 += cB.x*wv; pB1 += cB.y*wv; pB2 += cB.z*wv;
        }
    }
    __syncthreads();

    const int posA = h*32 + ((o + rot2) & 31);
    const int posB = h*32 + ((o + 16 + rot2) & 31);

    // B3: dtp2 (weighted)
    {
        float4 wA = w4[mA*128 + c];
        float4 wB = w4[mB*128 + c];
        ch[mA*256 + posA] = make_float4(pAs*evAx*wA.z, pAs*evAy*wA.z, pAs*evAz*wA.z, pAs*esA*wA.x);
        float dA = pA0*evAx + pA1*evAy + pA2*evAz;
        ch[mA*256 + posB] = make_float4(esA*pA0*wA.w, esA*pA1*wA.w, esA*pA2*wA.w, dA*wA.y);
        ch[mB*256 + posA] = make_float4(pBs*evBx*wB.z, pBs*evBy*wB.z, pBs*evBz*wB.z, pBs*esB*wB.x);
        float dB = pB0*evBx + pB1*evBy + pB2*evBz;
        ch[mB*256 + posB] = make_float4(esB*pB0*wB.w, esB*pB1*wB.w, esB*pB2*wB.w, dB*wB.y);
    }
    __syncthreads();

    // B4: Wagv
    float gtA, vlA, vA0, vA1, vA2, gtB, vlB, vB0, vB1, vB2;
    {
        const float bag0 = bagv[h*48 + o];
        const float bag1 = bagv[h*48 + 16 + o];
        const float bag2 = bagv[h*48 + 32 + o];
        float atA = bag0, atB = bag0;
        gtA = bag1; vlA = bag2; vA0 = 0.f; vA1 = 0.f; vA2 = 0.f;
        gtB = bag1; vlB = bag2; vB0 = 0.f; vB1 = 0.f; vB2 = 0.f;
        #pragma unroll 4
        for (int i = 0; i < 32; ++i) {
            int ph = (i + rot2) & 31;
            float4 cA = ch[chA + ph];
            float4 cB = ch[chB + ph];
            const float* wrow = &Wagv_s[(h*32+i)*48];
            float w0 = wrow[o], w1 = wrow[16+o], w2 = wrow[32+o];
            float wv = Wagv_v[(h*32+i)*16 + o];
            atA += cA.w*w0; gtA += cA.w*w1; vlA += cA.w*w2;
            vA0 += cA.x*wv; vA1 += cA.y*wv; vA2 += cA.z*wv;
            atB += cB.w*w0; gtB += cB.w*w1; vlB += cB.w*w2;
            vB0 += cB.x*wv; vB1 += cB.y*wv; vB2 += cB.z*wv;
        }
        afeat[(mA*8 + h)*17 + o] = atA;
        afeat[(mB*8 + h)*17 + o] = atB;
    }
    __syncthreads();

    // B5: logits (wave 0: 8 slots x 8 heads) + group max/den via shuffles
    if (t < EPB*H_N) {
        int m2 = t >> 3, h2 = t & 7;
        const float* afr = &afeat[(m2*8 + h2)*17];
        float mu = 0.f;
        #pragma unroll 4
        for (int d2 = 0; d2 < DH_N; ++d2) mu += afr[d2];
        mu *= (1.f/DH_N);
        float var = 0.f;
        #pragma unroll 4
        for (int d2 = 0; d2 < DH_N; ++d2) { float dd = afr[d2]-mu; var += dd*dd; }
        var *= (1.f/DH_N);
        float rstd = rsqrtf(var + EPS_F);
        float logit = 0.f;
        #pragma unroll 4
        for (int d2 = 0; d2 < DH_N; ++d2) {
            float xn = (afr[d2]-mu)*rstd*lna_g[d2] + lna_b[d2];
            logit += xn*Wattn[d2];
        }
        int jj = (g<<3) + m2;
        bool vok = jj < u;
        if (vok) {
            int kor = kidx[base + jj];
            attn_raw[h2*(N_Q*K_E) + n*K_E + kor] = logit;
        } else {
            logit = NEGMAX;            // clamped duplicate slot: exact 0 weight
        }
        afeat[(m2*8 + h2)*17 + 16] = logit;
        float mx = logit;
        mx = fmaxf(mx, __shfl_xor(mx, 8));
        mx = fmaxf(mx, __shfl_xor(mx, 16));
        mx = fmaxf(mx, __shfl_xor(mx, 32));
        float ex = expf(logit - mx);
        ex += __shfl_xor(ex, 8);
        ex += __shfl_xor(ex, 16);
        ex += __shfl_xor(ex, 32);
        if (m2 == 0) { mred[h2] = mx; mred[8 + h2] = ex; }
    }
    // gating (register-only, all threads)
    float sactA = vlA / (1.f + expf(-vlA));
    float gA = 1.f / (1.f + expf(-gtA));
    float qA0 = vA0*gA, qA1 = vA1*gA, qA2 = vA2*gA;
    float sactB = vlB / (1.f + expf(-vlB));
    float gB = 1.f / (1.f + expf(-gtB));
    float qB0 = vB0*gB, qB1 = vB1*gB, qB2 = vB2*gB;

    // B6: dtp3
    {
        ch[mA*256 + posA] = make_float4(sactA*evAx, sactA*evAy, sactA*evAz, sactA*esA);
        float dA = qA0*evAx + qA1*evAy + qA2*evAz;
        ch[mA*256 + posB] = make_float4(esA*qA0, esA*qA1, esA*qA2, dA);
        ch[mB*256 + posA] = make_float4(sactB*evBx, sactB*evBy, sactB*evBz, sactB*esB);
        float dB = qB0*evBx + qB1*evBy + qB2*evBz;
        ch[mB*256 + posB] = make_float4(esB*qB0, esB*qB1, esB*qB2, dB);
    }
    __syncthreads();

    // B7: Wval -> registers, weight by exp(logit - Mg), stage partial in w4
    {
        const float bval_r = bval[o];
        float vsA = bval_r, uA0 = 0.f, uA1 = 0.f, uA2 = 0.f;
        float vsB = bval_r, uB0 = 0.f, uB1 = 0.f, uB2 = 0.f;
        #pragma unroll 4
        for (int i = 0; i < 32; ++i) {
            int ph = (i + rot2) & 31;
            float4 cA = ch[chA + ph];
            float4 cB = ch[chB + ph];
            float ws = Wval_s[i*16 + o];
            float wv = Wval_v[i*16 + o];
            vsA += cA.w*ws; uA0 += cA.x*wv; uA1 += cA.y*wv; uA2 += cA.z*wv;
            vsB += cB.w*ws; uB0 += cB.x*wv; uB1 += cB.y*wv; uB2 += cB.z*wv;
        }
        float lA = afeat[(mA*8 + h)*17 + 16];
        float lB = afeat[(mB*8 + h)*17 + 16];
        float Mg = mred[h];
        float wgA = expf(lA - Mg);     // invalid slot: exp(-inf)=0 exact
        float wgB = expf(lB - Mg);
        w4[s*128 + c] = make_float4(wgA*uA0 + wgB*uB0, wgA*uA1 + wgB*uB1,
                                    wgA*uA2 + wgB*uB2, wgA*vsA + wgB*vsB);
    }
    __syncthreads();

    // tail: combine 4 s-slots -> one partial float4 per channel; emit Mg/deng
    if (t < 128) {
        float4 a = w4[t], b4 = w4[128 + t], c4 = w4[256 + t], d4 = w4[384 + t];
        pbuf[((size_t)(n*4 + g))*D_F + t] =
            make_float4(a.x + b4.x + c4.x + d4.x, a.y + b4.y + c4.y + d4.y,
                        a.z + b4.z + c4.z + d4.z, a.w + b4.w + c4.w + d4.w);
    } else if (t < 144) {
        mbuf[(n*4 + g)*16 + (t - 128)] = mred[t - 128];
    }
}

// ---------------------------------------------------------------------------
// k_finish: combine active flash partials, softmax probs from raw logits,
// Wo linear + skip add.
// ---------------------------------------------------------------------------
__global__ __launch_bounds__(128) void k_finish(
    const float4* __restrict__ pbuf, const float* __restrict__ mbuf,
    float* __restrict__ attn_out,     // in: raw logits, out: probabilities
    const float* __restrict__ skip_s, const float* __restrict__ skip_v,
    const float* __restrict__ Wo_s, const float* __restrict__ Wo_v, const float* __restrict__ bo,
    float* __restrict__ out0, float* __restrict__ out1)
{
    const int n = blockIdx.x, t = threadIdx.x;
    __shared__ float Ms[H_N], Dn[H_N];
    __shared__ float4 xsh[D_F];
    if (t < 32) {
        int h3 = t >> 2, g3 = t & 3;
        float mg = mbuf[(n*4 + g3)*16 + h3];
        float dg = mbuf[(n*4 + g3)*16 + 8 + h3];
        float mx = mg;
        mx = fmaxf(mx, __shfl_xor(mx, 1));
        mx = fmaxf(mx, __shfl_xor(mx, 2));
        float dsc = dg * expf(mg - mx);   // dead group: 0 * 0
        dsc += __shfl_xor(dsc, 1);
        dsc += __shfl_xor(dsc, 2);
        if (g3 == 0) { Ms[h3] = mx; Dn[h3] = dsc; }
    }
    __syncthreads();
    const int h = t >> 4, o = t & 15;
    const float M = Ms[h];
    const float rden = 1.f / Dn[h];
    float4 acc = make_float4(0.f, 0.f, 0.f, 0.f);
    #pragma unroll
    for (int gg = 0; gg < 4; ++gg) {
        float mg = mbuf[(n*4 + gg)*16 + h];
        if (mg > -1e37f) {             // skip dead groups (pbuf unwritten)
            float4 pv = pbuf[((size_t)(n*4 + gg))*D_F + t];
            float sf = expf(mg - M) * rden;
            acc.x += pv.x*sf; acc.y += pv.y*sf; acc.z += pv.z*sf; acc.w += pv.w*sf;
        }
    }
    xsh[t] = acc;
    #pragma unroll
    for (int kk = 0; kk < 2; ++kk) {
        size_t idx = (size_t)h*(N_Q*K_E) + (size_t)n*K_E + (o + kk*16);
        attn_out[idx] = expf(attn_out[idx] - M) * rden;
    }
    __syncthreads();
    float acc_s = bo[t], o0 = 0.f, o1 = 0.f, o2 = 0.f;
    #pragma unroll 4
    for (int i = 0; i < D_F; ++i) {
        float4 x = xsh[i];
        float ws = Wo_s[i*D_F + t];
        float wv = Wo_v[i*D_F + t];
        acc_s += x.w*ws; o0 += x.x*wv; o1 += x.y*wv; o2 += x.z*wv;
    }
    out0[n*D_F + t] = acc_s + skip_s[n*D_F + t];
    out1[(n*D_F + t)*3 + 0] = o0 + skip_v[(n*D_F + t)*3 + 0];
    out1[(n*D_F + t)*3 + 1] = o1 + skip_v[(n*D_F + t)*3 + 1];
    out1[(n*D_F + t)*3 + 2] = o2 + skip_v[(n*D_F + t)*3 + 2];
}

// ---------------------------------------------------------------------------
extern "C" void kernel_launch(void* const* d_in, const int* in_sizes, int n_in,
                              void* d_out, int out_size, void* d_ws, size_t ws_size,
                              hipStream_t stream)
{
    (void)in_sizes; (void)n_in; (void)out_size; (void)ws_size;

    const float* query_s = (const float*)d_in[0];
    const float* query_v = (const float*)d_in[1];
    const float* key_s   = (const float*)d_in[2];
    const float* key_v   = (const float*)d_in[3];
    const float* eis     = (const float*)d_in[4];
    const float* eiv     = (const float*)d_in[5];
    const float* eemb    = (const float*)d_in[6];
    const int*   mask    = (const int*)d_in[7];
    const int*   knn     = (const int*)d_in[8];
    const float* Wq_s    = (const float*)d_in[9];
    const float* Wq_v    = (const float*)d_in[10];
    const float* bq      = (const float*)d_in[11];
    const float* Wk_s    = (const float*)d_in[12];
    const float* Wk_v    = (const float*)d_in[13];
    const float* bk      = (const float*)d_in[14];
    const float* Wqk_s   = (const float*)d_in[15];
    const float* Wqk_v   = (const float*)d_in[16];
    const float* bqk     = (const float*)d_in[17];
    const float* Wdtp    = (const float*)d_in[18];
    const float* bdtp    = (const float*)d_in[19];
    const float* Wagv_s  = (const float*)d_in[20];
    const float* bagv    = (const float*)d_in[21];
    const float* Wagv_v  = (const float*)d_in[22];
    const float* Wattn   = (const float*)d_in[23];
    const float* Wval_s  = (const float*)d_in[24];
    const float* Wval_v  = (const float*)d_in[25];
    const float* bval    = (const float*)d_in[26];
    const float* Wo_s    = (const float*)d_in[27];
    const float* Wo_v    = (const float*)d_in[28];
    const float* bo      = (const float*)d_in[29];
    const float* ln_gs   = (const float*)d_in[30];
    const float* ln_bs   = (const float*)d_in[31];
    const float* ln_gv   = (const float*)d_in[32];
    const float* lna_g   = (const float*)d_in[33];
    const float* lna_b   = (const float*)d_in[34];

    float* out      = (float*)d_out;
    float* out_s    = out;
    float* out_v    = out + N_Q*D_F;
    float* out_attn = out + N_Q*D_F*4;

    float* ws = (float*)d_ws;
    float4* q4     = (float4*)ws;                      // N*128 f4 = 4 MB
    float4* k4     = q4 + N_Q*D_F;                     // 4 MB
    float*  skip_s = (float*)(k4 + N_Q*D_F);           // 1 MB
    float*  skip_v = skip_s + N_Q*D_F;                 // 3 MB
    float4* pbuf   = (float4*)(skip_v + N_Q*D_F*3);    // N*4*128 f4 = 16 MB
    float*  mbuf   = (float*)(pbuf + N_Q*4*D_F);       // N*4*16 f = 512 KB
    int*    kidx   = (int*)(mbuf + N_Q*4*16);          // N*K ints = 256 KB
    int*    ucnt   = kidx + N_Q*K_E;                   // N ints

    hipLaunchKernelGGL(k_prep, dim3(N_Q), dim3(64), 0, stream,
                       mask, kidx, ucnt, out_attn, mbuf);
    hipLaunchKernelGGL(k_qk, dim3(2*N_Q), dim3(D_F), 0, stream,
                       query_s, query_v, key_s, key_v,
                       Wq_s, Wq_v, bq, Wk_s, Wk_v, bk,
                       ln_gs, ln_bs, ln_gv,
                       q4, k4, skip_s, skip_v);
    hipLaunchKernelGGL(k_edge_flash, dim3(N_Q*K_E/EPB), dim3(512), 0, stream,
                       q4, k4, eis, eiv, eemb, knn, kidx, ucnt,
                       Wqk_s, Wqk_v, bqk, Wdtp, bdtp,
                       Wagv_s, bagv, Wagv_v, Wattn, lna_g, lna_b,
                       Wval_s, Wval_v, bval,
                       pbuf, mbuf, out_attn);
    hipLaunchKernelGGL(k_finish, dim3(N_Q), dim3(D_F), 0, stream,
                       pbuf, mbuf, out_attn, skip_s, skip_v, Wo_s, Wo_v, bo,
                       out_s, out_v);
}